// Round 7
// baseline (86.552 us; speedup 1.0000x reference)
//
#include <hip/hip_runtime.h>
#include <math.h>

#define NN 256
#define DD 128

typedef float4 f4;

#define FMA4(acc, s, v)                          \
  acc.x = fmaf(s, v.x, acc.x);                   \
  acc.y = fmaf(s, v.y, acc.y);                   \
  acc.z = fmaf(s, v.z, acc.z);                   \
  acc.w = fmaf(s, v.w, acc.w);

#define FMA4R(acc, a, p, v)                              \
  acc.x = fmaf(a, fmaxf(p.x + v.x, 0.f), acc.x);         \
  acc.y = fmaf(a, fmaxf(p.y + v.y, 0.f), acc.y);         \
  acc.z = fmaf(a, fmaxf(p.z + v.z, 0.f), acc.z);         \
  acc.w = fmaf(a, fmaxf(p.w + v.w, 0.f), acc.w);

#define ZERO4 {0.f, 0.f, 0.f, 0.f}

// Stage 128 KB global -> LDS via global_load_lds width=16 (no VGPR round-trip).
// 512 threads = 8 waves; each wave issues 16 x 1KB chunks.
__device__ __forceinline__ void stage_128k(const float* __restrict__ g,
                                           float* l, int tid) {
    const int wave = tid >> 6, lane = tid & 63;
    #pragma unroll
    for (int k = 0; k < 16; ++k) {
        const int chunk = wave * 16 + k;              // 0..127, 1 KB each
        __builtin_amdgcn_global_load_lds(
            (__attribute__((address_space(1))) void*)(void*)(g + chunk * 256 + lane * 4),
            (__attribute__((address_space(3))) void*)(l + chunk * 256),
            16, 0, 0);
    }
}

// ---------------------------------------------------------------------------
// h1_kernel: H1a = emb@W1a + mb1 ; H1b = emb@W1b
// 256 blocks x 512 threads, 4 rows/block. mW1 (128 KB) staged in LDS via
// global_load_lds; reduce buffer overlaid on the dead staging region.
// ---------------------------------------------------------------------------
__global__ __launch_bounds__(512, 2) void h1_kernel(
    const float* __restrict__ emb,   // [1024][128]
    const float* __restrict__ mW1,   // [256][128]
    const float* __restrict__ mb1,   // [128]
    float* __restrict__ H1a,
    float* __restrict__ H1b)
{
    const int tid  = threadIdx.x;
    const int row0 = blockIdx.x * 4;

    __shared__ float WL[32768];      // 128 KB: mW1; later overlaid by red (32 KB)
    __shared__ f4 embT[DD];          // 2 KB : embT[k] = emb[row0+0..3][k]

    // emb load first (early vmcnt slot), then the LDS-direct staging
    const int rs = tid >> 7, ks = tid & 127;
    const float ev = emb[(size_t)(row0 + rs) * DD + ks];
    stage_128k(mW1, WL, tid);
    ((float*)embT)[ks * 4 + rs] = ev;
    __syncthreads();

    const int oq  = tid & 63;                // col-quad of 256 out cols
    const int kh  = tid >> 6;                // 0..7 : 16 k each
    const int wq  = oq & 31;
    const int wr0 = (oq < 32) ? 0 : DD;      // W1a rows / W1b rows
    const f4* __restrict__ WL4 = (const f4*)WL;

    f4 a0 = ZERO4, a1 = ZERO4, a2 = ZERO4, a3 = ZERO4;
    #pragma unroll
    for (int t = 0; t < 16; ++t) {
        const int k = kh * 16 + t;
        const f4 w  = WL4[(wr0 + k) * 32 + wq];   // conflict-free b128
        const f4 e4 = embT[k];                    // wave-uniform broadcast
        FMA4(a0, e4.x, w);
        FMA4(a1, e4.y, w);
        FMA4(a2, e4.z, w);
        FMA4(a3, e4.w, w);
    }
    __syncthreads();                 // all WL reads done -> safe to overlay

    f4* red4 = (f4*)WL;              // [kh][r][oq] : 8*4*64 f4 = 32 KB
    red4[(kh * 4 + 0) * 64 + oq] = a0;
    red4[(kh * 4 + 1) * 64 + oq] = a1;
    red4[(kh * 4 + 2) * 64 + oq] = a2;
    red4[(kh * 4 + 3) * 64 + oq] = a3;
    __syncthreads();

    const float* __restrict__ redF = (const float*)WL;
    #pragma unroll
    for (int t = 0; t < 2; ++t) {
        const int o  = t * 512 + tid;
        const int rr = o >> 8, oc = o & 255;
        float v = 0.f;
        #pragma unroll
        for (int q = 0; q < 8; ++q) v += redF[(q * 4 + rr) * 256 + oc];
        if (oc < DD) H1a[(size_t)(row0 + rr) * DD + oc]        = v + mb1[oc];
        else         H1b[(size_t)(row0 + rr) * DD + (oc - DD)] = v;
    }
}

// ---------------------------------------------------------------------------
// gnn_kernel: 256 blocks x 512 threads, 4 output rows/block.
// H1b[b] (128 KB) staged in LDS via global_load_lds; reduce buffer overlaid
// after the j-loop. Small per-thread arrays only (wv[8]) -> no spill risk.
// ---------------------------------------------------------------------------
__global__ __launch_bounds__(512, 2) void gnn_kernel(
    const float* __restrict__ emb,
    const float* __restrict__ coords,  // [B][256][3]
    const float* __restrict__ mW2, const float* __restrict__ mb2,
    const float* __restrict__ uW1, const float* __restrict__ ub1,
    const float* __restrict__ uW2, const float* __restrict__ ub2,
    const float* __restrict__ H1a, const float* __restrict__ H1b,
    float* __restrict__ out)
{
    const int tid  = threadIdx.x;
    const int row0 = blockIdx.x * 4;
    const int b    = row0 >> 8;
    const int i0   = row0 & 255;

    __shared__ float HbL[32768];       // 128 KB: H1b[b]; red (32 KB) overlays after J
    __shared__ float cS[NN * 3];       // 3 KB
    __shared__ f4 As4[NN];             // 4 KB : As4[j] = A[0..3][j]
    __shared__ f4 R_T[DD];             // 2 KB : R_T[k] = R[0..3][k]
    __shared__ f4 U_T[DD + 3];         // 2.1 KB
    __shared__ f4 h_T[DD];             // 2 KB
    __shared__ f4 sAs4[16];
    __shared__ float sAtot[4];
    // ~141.5 KB total

    const int eq = tid & 31;           // e-quad
    const int js = tid >> 5;           // 0..15 (j-split; doubles as kh in GEMVs)

    // ---- P0: early loads (pa, cS, scalars) then LDS-direct H1b staging
    const f4* __restrict__ Ha4 = (const f4*)(H1a + (size_t)row0 * DD);
    const f4 pa0 = Ha4[0 * 32 + eq];
    const f4 pa1 = Ha4[1 * 32 + eq];
    const f4 pa2 = Ha4[2 * 32 + eq];
    const f4 pa3 = Ha4[3 * 32 + eq];
    const int rr2 = tid >> 7, ea = tid & 127;
    const float embv = emb[(size_t)(row0 + rr2) * DD + ea];
    const float mb2v = mb2[ea], ub1v = ub1[ea], ub2v = ub2[ea];
    const float* __restrict__ cb = coords + (size_t)b * NN * 3;
    f4 cldv = ZERO4;
    if (tid < 192) cldv = ((const f4*)cb)[tid];

    stage_128k(H1b + (size_t)b * NN * DD, HbL, tid);
    if (tid < 192) ((f4*)cS)[tid] = cldv;
    __syncthreads();

    // ---- P1: A rows (thread j = tid&255, rA = tid>>8 -> rows rA, rA+2)
    {   const int j = tid & 255, rA = tid >> 8;
        const float cjx = cS[j * 3], cjy = cS[j * 3 + 1], cjz = cS[j * 3 + 2];
        float* __restrict__ AsF = (float*)As4;
        {   const int ii = i0 + rA;
            const float dx = cjx - cS[ii * 3], dy = cjy - cS[ii * 3 + 1], dz = cjz - cS[ii * 3 + 2];
            AsF[j * 4 + rA] = __expf(-0.5f * (dx * dx + dy * dy + dz * dz)); }
        {   const int ii = i0 + rA + 2;
            const float dx = cjx - cS[ii * 3], dy = cjy - cS[ii * 3 + 1], dz = cjz - cS[ii * 3 + 2];
            AsF[j * 4 + rA + 2] = __expf(-0.5f * (dx * dx + dy * dy + dz * dz)); }
    }
    __syncthreads();

    // ---- P2 (J): 16 j per thread, all operands from LDS
    const f4* __restrict__ Hb4 = (const f4*)HbL;
    f4 a0 = ZERO4, a1 = ZERO4, a2 = ZERO4, a3 = ZERO4, sA4 = ZERO4;
    #pragma unroll
    for (int t = 0; t < 16; ++t) {
        const int j = js * 16 + t;
        const f4 a = As4[j];               // half-wave-uniform broadcast
        const f4 v = Hb4[j * 32 + eq];     // conflict-free b128
        sA4.x += a.x; sA4.y += a.y; sA4.z += a.z; sA4.w += a.w;
        FMA4R(a0, a.x, pa0, v);
        FMA4R(a1, a.y, pa1, v);
        FMA4R(a2, a.z, pa2, v);
        FMA4R(a3, a.w, pa3, v);
    }
    __syncthreads();                   // HbL reads done -> overlay red

    // ---- P3: dump partials into overlaid red; prefetch G1 weights
    f4* red4 = (f4*)HbL;               // [part 0..15][r][eq] = 32 KB
    red4[(js * 4 + 0) * 32 + eq] = a0;
    red4[(js * 4 + 1) * 32 + eq] = a1;
    red4[(js * 4 + 2) * 32 + eq] = a2;
    red4[(js * 4 + 3) * 32 + eq] = a3;
    if (eq == 0) sAs4[js] = sA4;
    const int kh = js, cq = eq;
    f4 wv[8];
    {   const f4* __restrict__ W2g = (const f4*)mW2;
        #pragma unroll
        for (int t = 0; t < 8; ++t) wv[t] = W2g[(size_t)(kh * 8 + t) * 32 + cq];
    }
    __syncthreads();

    // ---- P4 (R): reduce 16 partials -> R_T ; sAtot
    const float* __restrict__ redF = (const float*)HbL;
    {   const int r = tid >> 7, e = tid & 127;
        float s = 0.f;
        #pragma unroll
        for (int q = 0; q < 16; ++q) s += redF[(q * 4 + r) * 128 + e];
        ((float*)R_T)[e * 4 + r] = s;
    }
    if (tid < 4) {
        const float* __restrict__ sF = (const float*)sAs4;
        float s = 0.f;
        #pragma unroll
        for (int q = 0; q < 16; ++q) s += sF[q * 4 + tid];
        sAtot[tid] = s;
    }
    __syncthreads();

    // ---- P5 (G1): agg-partials = R @ mW2 ; prefetch G2 weights (+tail)
    {   f4 g0 = ZERO4, g1 = ZERO4, g2 = ZERO4, g3 = ZERO4;
        #pragma unroll
        for (int t = 0; t < 8; ++t) {
            const f4 rv = R_T[kh * 8 + t];
            FMA4(g0, rv.x, wv[t]);
            FMA4(g1, rv.y, wv[t]);
            FMA4(g2, rv.z, wv[t]);
            FMA4(g3, rv.w, wv[t]);
        }
        red4[(kh * 4 + 0) * 32 + cq] = g0;
        red4[(kh * 4 + 1) * 32 + cq] = g1;
        red4[(kh * 4 + 2) * 32 + cq] = g2;
        red4[(kh * 4 + 3) * 32 + cq] = g3;
    }
    f4 wt0 = ZERO4, wt1 = ZERO4, wt2 = ZERO4;
    {   const f4* __restrict__ U1g = (const f4*)uW1;
        #pragma unroll
        for (int t = 0; t < 8; ++t) wv[t] = U1g[(size_t)(kh * 8 + t) * 32 + cq];
        if (kh == 15) {
            wt0 = U1g[(size_t)(DD + 0) * 32 + cq];
            wt1 = U1g[(size_t)(DD + 1) * 32 + cq];
            wt2 = U1g[(size_t)(DD + 2) * 32 + cq];
        }
    }
    __syncthreads();

    // ---- P6 (U): reduce + assemble upd_in (agg + sA*mb2; coords tail)
    {   const int r = tid >> 7, e = tid & 127;
        float s = sAtot[r] * mb2v;
        #pragma unroll
        for (int q = 0; q < 16; ++q) s += redF[(q * 4 + r) * 128 + e];
        ((float*)U_T)[e * 4 + r] = s;
    }
    if (tid < 12) {
        const int r = tid & 3, c = tid >> 2;
        ((float*)U_T)[(DD + c) * 4 + r] = cS[(i0 + r) * 3 + c];
    }
    __syncthreads();

    // ---- P7 (G2): hid-partials = upd_in @ uW1 (kh==15 adds 3 tail rows)
    {   f4 g0 = ZERO4, g1 = ZERO4, g2 = ZERO4, g3 = ZERO4;
        #pragma unroll
        for (int t = 0; t < 8; ++t) {
            const f4 uv = U_T[kh * 8 + t];
            FMA4(g0, uv.x, wv[t]);
            FMA4(g1, uv.y, wv[t]);
            FMA4(g2, uv.z, wv[t]);
            FMA4(g3, uv.w, wv[t]);
        }
        if (kh == 15) {
            const f4 uv0 = U_T[DD + 0], uv1 = U_T[DD + 1], uv2 = U_T[DD + 2];
            FMA4(g0, uv0.x, wt0); FMA4(g1, uv0.y, wt0); FMA4(g2, uv0.z, wt0); FMA4(g3, uv0.w, wt0);
            FMA4(g0, uv1.x, wt1); FMA4(g1, uv1.y, wt1); FMA4(g2, uv1.z, wt1); FMA4(g3, uv1.w, wt1);
            FMA4(g0, uv2.x, wt2); FMA4(g1, uv2.y, wt2); FMA4(g2, uv2.z, wt2); FMA4(g3, uv2.w, wt2);
        }
        red4[(kh * 4 + 0) * 32 + cq] = g0;
        red4[(kh * 4 + 1) * 32 + cq] = g1;
        red4[(kh * 4 + 2) * 32 + cq] = g2;
        red4[(kh * 4 + 3) * 32 + cq] = g3;
    }
    {   const f4* __restrict__ U2g = (const f4*)uW2;
        #pragma unroll
        for (int t = 0; t < 8; ++t) wv[t] = U2g[(size_t)(kh * 8 + t) * 32 + cq];
    }
    __syncthreads();

    // ---- P8 (H): reduce + relu -> h_T
    {   const int r = tid >> 7, e = tid & 127;
        float s = ub1v;
        #pragma unroll
        for (int q = 0; q < 16; ++q) s += redF[(q * 4 + r) * 128 + e];
        ((float*)h_T)[e * 4 + r] = fmaxf(s, 0.f);
    }
    __syncthreads();

    // ---- P9 (G3): delta-partials = hid @ uW2
    {   f4 g0 = ZERO4, g1 = ZERO4, g2 = ZERO4, g3 = ZERO4;
        #pragma unroll
        for (int t = 0; t < 8; ++t) {
            const f4 hv = h_T[kh * 8 + t];
            FMA4(g0, hv.x, wv[t]);
            FMA4(g1, hv.y, wv[t]);
            FMA4(g2, hv.z, wv[t]);
            FMA4(g3, hv.w, wv[t]);
        }
        red4[(kh * 4 + 0) * 32 + cq] = g0;
        red4[(kh * 4 + 1) * 32 + cq] = g1;
        red4[(kh * 4 + 2) * 32 + cq] = g2;
        red4[(kh * 4 + 3) * 32 + cq] = g3;
    }
    __syncthreads();

    // ---- P10: final reduce + residual
    {   const int r = tid >> 7, e = tid & 127;
        float s = ub2v;
        #pragma unroll
        for (int q = 0; q < 16; ++q) s += redF[(q * 4 + r) * 128 + e];
        out[(size_t)(row0 + r) * DD + e] = embv + s;
    }
}

extern "C" void kernel_launch(void* const* d_in, const int* in_sizes, int n_in,
                              void* d_out, int out_size, void* d_ws, size_t ws_size,
                              hipStream_t stream) {
    const float* emb    = (const float*)d_in[0];
    const float* coords = (const float*)d_in[1];
    const float* mW1    = (const float*)d_in[2];
    const float* mb1    = (const float*)d_in[3];
    const float* mW2    = (const float*)d_in[4];
    const float* mb2    = (const float*)d_in[5];
    const float* uW1    = (const float*)d_in[6];
    const float* ub1    = (const float*)d_in[7];
    const float* uW2    = (const float*)d_in[8];
    const float* ub2    = (const float*)d_in[9];
    float* out = (float*)d_out;

    float* H1a = (float*)d_ws;
    float* H1b = H1a + 4 * NN * DD;

    h1_kernel<<<dim3(256), dim3(512), 0, stream>>>(emb, mW1, mb1, H1a, H1b);
    gnn_kernel<<<dim3(256), dim3(512), 0, stream>>>(
        emb, coords, mW2, mb2, uW1, ub1, uW2, ub2, H1a, H1b, out);
}